// Round 1
// baseline (1044.342 us; speedup 1.0000x reference)
//
#include <hip/hip_runtime.h>
#include <hip/hip_bf16.h>

#define EMBED 640
#define CROSS 768
#define NH 8
#define HEAD 80
#define BATCH 8
#define SEQT 4096
#define SEQS 77

// ---------------------------------------------------------------------------
// GEMM: C[M,N] = A[M,K] @ W[K,N] + bias[N]   (fp32 vector ALU, no fp32 MFMA)
// BM=128 BN=128 BK=16, 256 threads, 8x8 microtile per thread.
// N must be a multiple of 128, K a multiple of 16 (true here: 640/768).
// ---------------------------------------------------------------------------
__global__ __launch_bounds__(256) void gemm_bias(
    const float* __restrict__ A, const float* __restrict__ W,
    const float* __restrict__ bias, float* __restrict__ C,
    int M, int N, int K)
{
    __shared__ __align__(16) float As[16][128];  // transposed A tile: As[k][m]
    __shared__ __align__(16) float Bs[16][128];  // Bs[k][n]

    const int tid = threadIdx.x;
    const int txn = tid & 15;        // 0..15 -> col group
    const int txm = tid >> 4;        // 0..15 -> row group
    const int m0 = blockIdx.y * 128;
    const int n0 = blockIdx.x * 128;

    // loader mapping
    const int alr = tid >> 2;           // 0..63   A row within tile
    const int alc = (tid & 3) << 2;     // 0,4,8,12 k chunk
    const int bkr = tid >> 4;           // 0..15   B row (k)
    const int bnc = (tid & 15) << 3;    // col chunk *8

    float acc[8][8] = {};

    for (int k0 = 0; k0 < K; k0 += 16) {
        // A tile: 128x16, two rows per thread, transpose into As[k][m]
        #pragma unroll
        for (int rr = 0; rr < 2; ++rr) {
            int m = m0 + alr + rr * 64;
            float4 av = make_float4(0.f, 0.f, 0.f, 0.f);
            if (m < M) av = *(const float4*)&A[(size_t)m * K + k0 + alc];
            As[alc + 0][alr + rr * 64] = av.x;
            As[alc + 1][alr + rr * 64] = av.y;
            As[alc + 2][alr + rr * 64] = av.z;
            As[alc + 3][alr + rr * 64] = av.w;
        }
        // B tile: 16x128, coalesced
        {
            const float* src = &W[(size_t)(k0 + bkr) * N + n0 + bnc];
            *(float4*)&Bs[bkr][bnc]     = *(const float4*)&src[0];
            *(float4*)&Bs[bkr][bnc + 4] = *(const float4*)&src[4];
        }
        __syncthreads();

        #pragma unroll
        for (int k = 0; k < 16; ++k) {
            float a[8], bb[8];
            *(float4*)&a[0]  = *(const float4*)&As[k][txm * 8];
            *(float4*)&a[4]  = *(const float4*)&As[k][txm * 8 + 4];
            *(float4*)&bb[0] = *(const float4*)&Bs[k][txn * 8];
            *(float4*)&bb[4] = *(const float4*)&Bs[k][txn * 8 + 4];
            #pragma unroll
            for (int i = 0; i < 8; ++i)
                #pragma unroll
                for (int j = 0; j < 8; ++j)
                    acc[i][j] += a[i] * bb[j];
        }
        __syncthreads();
    }

    // epilogue: + bias, store
    #pragma unroll
    for (int i = 0; i < 8; ++i) {
        int m = m0 + txm * 8 + i;
        if (m >= M) continue;
        #pragma unroll
        for (int j = 0; j < 8; j += 4) {
            int n = n0 + txn * 8 + j;
            float4 o;
            o.x = acc[i][j + 0] + bias[n + 0];
            o.y = acc[i][j + 1] + bias[n + 1];
            o.z = acc[i][j + 2] + bias[n + 2];
            o.w = acc[i][j + 3] + bias[n + 3];
            *(float4*)&C[(size_t)m * N + n] = o;
        }
    }
}

// ---------------------------------------------------------------------------
// K/V projection: rows = 616 (=8*77), K=768, N=640. Block handles 8 rows x
// 128 cols; y rows staged in LDS (broadcast reads), W loads coalesced.
// blockIdx.z selects K (0) or V (1).
// ---------------------------------------------------------------------------
__global__ __launch_bounds__(128) void kv_proj(
    const float* __restrict__ y,
    const float* __restrict__ Wk, const float* __restrict__ bk,
    const float* __restrict__ Wv, const float* __restrict__ bv,
    float* __restrict__ Ko, float* __restrict__ Vo)
{
    __shared__ __align__(16) float yl[8 * CROSS];  // 24.6 KB
    const int tid = threadIdx.x;
    const int n  = blockIdx.x * 128 + tid;
    const int r0 = blockIdx.y * 8;                 // 616 = 77*8 exactly
    const float* W    = blockIdx.z ? Wv : Wk;
    const float* bias = blockIdx.z ? bv : bk;
    float* out        = blockIdx.z ? Vo : Ko;

    for (int i = tid * 4; i < 8 * CROSS; i += 128 * 4)
        *(float4*)&yl[i] = *(const float4*)&y[(size_t)r0 * CROSS + i];
    __syncthreads();

    float acc[8];
    #pragma unroll
    for (int r = 0; r < 8; ++r) acc[r] = bias[n];

    #pragma unroll 4
    for (int kk = 0; kk < CROSS; ++kk) {
        float w = W[(size_t)kk * EMBED + n];
        #pragma unroll
        for (int r = 0; r < 8; ++r) acc[r] += yl[r * CROSS + kk] * w;
    }
    #pragma unroll
    for (int r = 0; r < 8; ++r)
        out[(size_t)(r0 + r) * EMBED + n] = acc[r];
}

// ---------------------------------------------------------------------------
// Fused attention, in-place on q. Block = 256 threads = 64 rows x 4 lanes.
// Each lane owns 20 of the 80 head dims. K tile then V tile share one LDS
// buffer (K needed only in pass 1, V only in pass 3). Scores per row in LDS.
// ---------------------------------------------------------------------------
__global__ __launch_bounds__(256) void attn(
    float* __restrict__ q,          // [BATCH*SEQT, EMBED], in/out
    const float* __restrict__ k,    // [BATCH*SEQS, EMBED]
    const float* __restrict__ v)    // [BATCH*SEQS, EMBED]
{
    __shared__ __align__(16) float kv[SEQS * HEAD];  // 24.6 KB (K, then V)
    __shared__ float sc[64 * SEQS];                  // 19.7 KB scores

    const int tid = threadIdx.x;
    const int bh  = blockIdx.y;
    const int b   = bh >> 3, h = bh & 7;
    const int ty  = tid >> 2, tx = tid & 3;
    const int t   = blockIdx.x * 64 + ty;

    // stage K tile for this (b,h): 77 x 80 floats
    for (int i = tid * 4; i < SEQS * HEAD; i += 256 * 4) {
        int s = i / HEAD, d = i % HEAD;
        *(float4*)&kv[i] = *(const float4*)&k[(size_t)(b * SEQS + s) * EMBED + h * HEAD + d];
    }
    __syncthreads();

    // own q chunk -> registers (these addresses are also our output slots)
    float qr[20];
    const size_t qbase = (size_t)(b * SEQT + t) * EMBED + h * HEAD + tx * 20;
    #pragma unroll
    for (int j = 0; j < 20; j += 4) *(float4*)&qr[j] = *(const float4*)&q[qbase + j];

    const float scale = 0.11180339887498949f;  // 1/sqrt(80)
    float mx = -1e30f;
    for (int s = 0; s < SEQS; ++s) {
        float p = 0.f;
        #pragma unroll
        for (int j = 0; j < 20; j += 4) {
            float4 kk4 = *(const float4*)&kv[s * HEAD + tx * 20 + j];
            p += qr[j] * kk4.x + qr[j + 1] * kk4.y + qr[j + 2] * kk4.z + qr[j + 3] * kk4.w;
        }
        p += __shfl_xor(p, 1);   // 4-lane reduce: all 4 lanes get full dot
        p += __shfl_xor(p, 2);
        p *= scale;
        if (tx == 0) sc[ty * SEQS + s] = p;
        mx = fmaxf(mx, p);       // identical across the 4 lanes of a row
    }
    __syncthreads();             // sc visible; K tile no longer needed

    // stage V tile into the same buffer (reads of it only after next barrier)
    for (int i = tid * 4; i < SEQS * HEAD; i += 256 * 4) {
        int s = i / HEAD, d = i % HEAD;
        *(float4*)&kv[i] = *(const float4*)&v[(size_t)(b * SEQS + s) * EMBED + h * HEAD + d];
    }

    // softmax denominator; overwrite sc with exp(p - mx).
    // (read+write of sc[ty][s] stay within one wave -> lockstep-safe)
    float l = 0.f;
    for (int s = 0; s < SEQS; ++s) {
        float e = __expf(sc[ty * SEQS + s] - mx);
        l += e;
        if (tx == 0) sc[ty * SEQS + s] = e;
    }
    __syncthreads();             // V tile + exp'd scores visible

    float acc[20] = {};
    for (int s = 0; s < SEQS; ++s) {
        float e = sc[ty * SEQS + s];
        #pragma unroll
        for (int j = 0; j < 20; j += 4) {
            float4 vv4 = *(const float4*)&kv[s * HEAD + tx * 20 + j];
            acc[j]     += e * vv4.x;
            acc[j + 1] += e * vv4.y;
            acc[j + 2] += e * vv4.z;
            acc[j + 3] += e * vv4.w;
        }
    }
    const float inv = 1.0f / l;
    #pragma unroll
    for (int j = 0; j < 20; j += 4) {
        float4 o;
        o.x = acc[j] * inv; o.y = acc[j + 1] * inv;
        o.z = acc[j + 2] * inv; o.w = acc[j + 3] * inv;
        *(float4*)&q[qbase + j] = o;
    }
}

// ---------------------------------------------------------------------------
extern "C" void kernel_launch(void* const* d_in, const int* in_sizes, int n_in,
                              void* d_out, int out_size, void* d_ws, size_t ws_size,
                              hipStream_t stream)
{
    const float* x  = (const float*)d_in[0];
    const float* y  = (const float*)d_in[1];
    const float* Wq = (const float*)d_in[2];
    const float* bq = (const float*)d_in[3];
    const float* Wk = (const float*)d_in[4];
    const float* bk = (const float*)d_in[5];
    const float* Wv = (const float*)d_in[6];
    const float* bv = (const float*)d_in[7];
    const float* Wo = (const float*)d_in[8];
    const float* bo = (const float*)d_in[9];
    float* out = (float*)d_out;

    float* qws = (float*)d_ws;                          // 8*4096*640 = 20,971,520 f
    float* kws = qws + (size_t)BATCH * SEQT * EMBED;    // 616*640
    float* vws = kws + (size_t)BATCH * SEQS * EMBED;

    const int M = BATCH * SEQT;  // 32768

    // 1) Q = x @ Wq + bq
    gemm_bias<<<dim3(EMBED / 128, (M + 127) / 128), 256, 0, stream>>>(
        x, Wq, bq, qws, M, EMBED, EMBED);
    // 2) K,V = y @ Wk/Wv + b
    kv_proj<<<dim3(EMBED / 128, (BATCH * SEQS) / 8, 2), 128, 0, stream>>>(
        y, Wk, bk, Wv, bv, kws, vws);
    // 3) fused attention, in-place on qws
    attn<<<dim3(SEQT / 64, BATCH * NH), 256, 0, stream>>>(qws, kws, vws);
    // 4) out = attn_out @ Wo + bo
    gemm_bias<<<dim3(EMBED / 128, (M + 127) / 128), 256, 0, stream>>>(
        qws, Wo, bo, out, M, EMBED, EMBED);
}

// Round 2
// 559.106 us; speedup vs baseline: 1.8679x; 1.8679x over previous
//
#include <hip/hip_runtime.h>
#include <hip/hip_bf16.h>
#include <hip/hip_fp16.h>

#define EMBED 640
#define CROSS 768
#define NH 8
#define HEAD 80
#define BATCH 8
#define SEQT 4096
#define SEQS 77
#define MROWS (BATCH * SEQT)

typedef _Float16 half8 __attribute__((ext_vector_type(8)));
typedef _Float16 half4v __attribute__((ext_vector_type(4)));
typedef float floatx4 __attribute__((ext_vector_type(4)));

__device__ __forceinline__ void lds_load16(const void* g, void* l) {
    __builtin_amdgcn_global_load_lds(
        (const __attribute__((address_space(1))) void*)g,
        (__attribute__((address_space(3))) void*)l, 16, 0, 0);
}

// ---------------------------------------------------------------------------
// fp32 -> f16 cast, 8 elems/thread. n must be divisible by 2048*8 (true: 21M).
// ---------------------------------------------------------------------------
__global__ __launch_bounds__(256) void cvt_f32_f16(
    const float* __restrict__ in, _Float16* __restrict__ out)
{
    size_t i = ((size_t)blockIdx.x * 256 + threadIdx.x) * 8;
    float4 a = *(const float4*)&in[i];
    float4 b = *(const float4*)&in[i + 4];
    half8 h;
    h[0] = (_Float16)a.x; h[1] = (_Float16)a.y;
    h[2] = (_Float16)a.z; h[3] = (_Float16)a.w;
    h[4] = (_Float16)b.x; h[5] = (_Float16)b.y;
    h[6] = (_Float16)b.z; h[7] = (_Float16)b.w;
    *(half8*)&out[i] = h;
}

// ---------------------------------------------------------------------------
// W [K,N] fp32  ->  Wt [N,K] f16   (tiled transpose, 32x32)
// ---------------------------------------------------------------------------
__global__ __launch_bounds__(256) void transpose_cvt(
    const float* __restrict__ W, _Float16* __restrict__ Wt, int K, int N)
{
    __shared__ float t[32][33];
    const int k0 = blockIdx.y * 32, n0 = blockIdx.x * 32;
    for (int r = threadIdx.y; r < 32; r += 8)
        t[r][threadIdx.x] = W[(size_t)(k0 + r) * N + n0 + threadIdx.x];
    __syncthreads();
    for (int r = threadIdx.y; r < 32; r += 8)
        Wt[(size_t)(n0 + r) * K + k0 + threadIdx.x] = (_Float16)t[threadIdx.x][r];
}

// ---------------------------------------------------------------------------
// f16 MFMA GEMM (m97 structure): C[M,N] = A[M,K] @ Bt[N,K]^T + bias.
// 128x128 tile, BK=32, 256 thr = 4 waves (2x2 of 64x64), 16x16x32 f16 MFMA.
// global_load_lds width=16 staging; M%128==0, N%128==0, K%32==0.
// ---------------------------------------------------------------------------
__global__ __launch_bounds__(256) void gemm_f16(
    const _Float16* __restrict__ A,   // [M,K] f16
    const _Float16* __restrict__ Bt,  // [N,K] f16
    const float* __restrict__ bias,
    float* __restrict__ C, int M, int N, int K)
{
    __shared__ _Float16 As[128 * 32];   // [m][k], row stride 32 (64 B)
    __shared__ _Float16 Bs[128 * 32];   // [n][k]

    const int tid  = threadIdx.x;
    const int wave = tid >> 6;
    const int lane = tid & 63;
    const int quad = lane >> 4;
    const int l16  = lane & 15;
    const int m0 = blockIdx.y * 128, n0 = blockIdx.x * 128;
    const int wm = (wave >> 1) * 64, wn = (wave & 1) * 64;

    const int row = tid >> 2;          // 0..63 staging row
    const int kch = (tid & 3) * 8;     // k chunk of 8 f16 (16 B)

    floatx4 acc[4][4] = {};

    for (int k0 = 0; k0 < K; k0 += 32) {
        const _Float16* ga0 = &A [(size_t)(m0 + row)      * K + k0 + kch];
        const _Float16* ga1 = &A [(size_t)(m0 + 64 + row) * K + k0 + kch];
        const _Float16* gb0 = &Bt[(size_t)(n0 + row)      * K + k0 + kch];
        const _Float16* gb1 = &Bt[(size_t)(n0 + 64 + row) * K + k0 + kch];
        // dest byte = r*4096 + wave*1024 + lane*16  (wave-uniform base + lane*16)
        lds_load16(ga0, &As[wave * 512]);
        lds_load16(ga1, &As[2048 + wave * 512]);
        lds_load16(gb0, &Bs[wave * 512]);
        lds_load16(gb1, &Bs[2048 + wave * 512]);
        __syncthreads();

        half8 a[4], b[4];
        #pragma unroll
        for (int i = 0; i < 4; ++i)
            a[i] = *(const half8*)&As[(wm + i * 16 + l16) * 32 + quad * 8];
        #pragma unroll
        for (int j = 0; j < 4; ++j)
            b[j] = *(const half8*)&Bs[(wn + j * 16 + l16) * 32 + quad * 8];
        #pragma unroll
        for (int i = 0; i < 4; ++i)
            #pragma unroll
            for (int j = 0; j < 4; ++j)
                acc[i][j] = __builtin_amdgcn_mfma_f32_16x16x32_f16(
                    a[i], b[j], acc[i][j], 0, 0, 0);
        __syncthreads();
    }

    // epilogue: C/D layout col = lane&15, row = quad*4 + reg (dtype-independent)
    float bcol[4];
    #pragma unroll
    for (int j = 0; j < 4; ++j) bcol[j] = bias[n0 + wn + j * 16 + l16];
    #pragma unroll
    for (int i = 0; i < 4; ++i)
        #pragma unroll
        for (int r = 0; r < 4; ++r) {
            const int m = m0 + wm + i * 16 + quad * 4 + r;
            #pragma unroll
            for (int j = 0; j < 4; ++j)
                C[(size_t)m * N + n0 + wn + j * 16 + l16] = acc[i][j][r] + bcol[j];
        }
}

// ---------------------------------------------------------------------------
// K/V projection (unchanged fp32): rows = 616, K=768, N=640.
// ---------------------------------------------------------------------------
__global__ __launch_bounds__(128) void kv_proj(
    const float* __restrict__ y,
    const float* __restrict__ Wk, const float* __restrict__ bk,
    const float* __restrict__ Wv, const float* __restrict__ bv,
    float* __restrict__ Ko, float* __restrict__ Vo)
{
    __shared__ __align__(16) float yl[8 * CROSS];
    const int tid = threadIdx.x;
    const int n  = blockIdx.x * 128 + tid;
    const int r0 = blockIdx.y * 8;
    const float* W    = blockIdx.z ? Wv : Wk;
    const float* bias = blockIdx.z ? bv : bk;
    float* out        = blockIdx.z ? Vo : Ko;

    for (int i = tid * 4; i < 8 * CROSS; i += 128 * 4)
        *(float4*)&yl[i] = *(const float4*)&y[(size_t)r0 * CROSS + i];
    __syncthreads();

    float acc[8];
    #pragma unroll
    for (int r = 0; r < 8; ++r) acc[r] = bias[n];

    #pragma unroll 4
    for (int kk = 0; kk < CROSS; ++kk) {
        float w = W[(size_t)kk * EMBED + n];
        #pragma unroll
        for (int r = 0; r < 8; ++r) acc[r] += yl[r * CROSS + kk] * w;
    }
    #pragma unroll
    for (int r = 0; r < 8; ++r)
        out[(size_t)(r0 + r) * EMBED + n] = acc[r];
}

// ---------------------------------------------------------------------------
// Fused attention (fp32 math, unchanged) — now writes f16 for the O-proj GEMM.
// ---------------------------------------------------------------------------
__global__ __launch_bounds__(256) void attn(
    const float* __restrict__ q,    // [M, EMBED] fp32
    const float* __restrict__ k,
    const float* __restrict__ v,
    _Float16* __restrict__ o)       // [M, EMBED] f16
{
    __shared__ __align__(16) float kv[SEQS * HEAD];
    __shared__ float sc[64 * SEQS];

    const int tid = threadIdx.x;
    const int bh  = blockIdx.y;
    const int b   = bh >> 3, h = bh & 7;
    const int ty  = tid >> 2, tx = tid & 3;
    const int t   = blockIdx.x * 64 + ty;

    for (int i = tid * 4; i < SEQS * HEAD; i += 256 * 4) {
        int s = i / HEAD, d = i % HEAD;
        *(float4*)&kv[i] = *(const float4*)&k[(size_t)(b * SEQS + s) * EMBED + h * HEAD + d];
    }
    __syncthreads();

    float qr[20];
    const size_t qbase = (size_t)(b * SEQT + t) * EMBED + h * HEAD + tx * 20;
    #pragma unroll
    for (int j = 0; j < 20; j += 4) *(float4*)&qr[j] = *(const float4*)&q[qbase + j];

    const float scale = 0.11180339887498949f;  // 1/sqrt(80)
    float mx = -1e30f;
    for (int s = 0; s < SEQS; ++s) {
        float p = 0.f;
        #pragma unroll
        for (int j = 0; j < 20; j += 4) {
            float4 kk4 = *(const float4*)&kv[s * HEAD + tx * 20 + j];
            p += qr[j] * kk4.x + qr[j + 1] * kk4.y + qr[j + 2] * kk4.z + qr[j + 3] * kk4.w;
        }
        p += __shfl_xor(p, 1);
        p += __shfl_xor(p, 2);
        p *= scale;
        if (tx == 0) sc[ty * SEQS + s] = p;
        mx = fmaxf(mx, p);
    }
    __syncthreads();

    for (int i = tid * 4; i < SEQS * HEAD; i += 256 * 4) {
        int s = i / HEAD, d = i % HEAD;
        *(float4*)&kv[i] = *(const float4*)&v[(size_t)(b * SEQS + s) * EMBED + h * HEAD + d];
    }

    float l = 0.f;
    for (int s = 0; s < SEQS; ++s) {
        float e = __expf(sc[ty * SEQS + s] - mx);
        l += e;
        if (tx == 0) sc[ty * SEQS + s] = e;
    }
    __syncthreads();

    float acc[20] = {};
    for (int s = 0; s < SEQS; ++s) {
        float e = sc[ty * SEQS + s];
        #pragma unroll
        for (int j = 0; j < 20; j += 4) {
            float4 vv4 = *(const float4*)&kv[s * HEAD + tx * 20 + j];
            acc[j]     += e * vv4.x;
            acc[j + 1] += e * vv4.y;
            acc[j + 2] += e * vv4.z;
            acc[j + 3] += e * vv4.w;
        }
    }
    const float inv = 1.0f / l;
    #pragma unroll
    for (int j = 0; j < 20; j += 4) {
        half4v hv;
        hv[0] = (_Float16)(acc[j]     * inv);
        hv[1] = (_Float16)(acc[j + 1] * inv);
        hv[2] = (_Float16)(acc[j + 2] * inv);
        hv[3] = (_Float16)(acc[j + 3] * inv);
        *(half4v*)&o[qbase + j] = hv;
    }
}

// ---------------------------------------------------------------------------
extern "C" void kernel_launch(void* const* d_in, const int* in_sizes, int n_in,
                              void* d_out, int out_size, void* d_ws, size_t ws_size,
                              hipStream_t stream)
{
    const float* x  = (const float*)d_in[0];
    const float* y  = (const float*)d_in[1];
    const float* Wq = (const float*)d_in[2];
    const float* bq = (const float*)d_in[3];
    const float* Wk = (const float*)d_in[4];
    const float* bk = (const float*)d_in[5];
    const float* Wv = (const float*)d_in[6];
    const float* bv = (const float*)d_in[7];
    const float* Wo = (const float*)d_in[8];
    const float* bo = (const float*)d_in[9];
    float* out = (float*)d_out;

    const size_t ME = (size_t)MROWS * EMBED;            // 20,971,520
    float*    qws = (float*)d_ws;                       // fp32 Q        (84 MB)
    float*    kws = qws + ME;                           // fp32 K proj
    float*    vws = kws + (size_t)BATCH * SEQS * EMBED; // fp32 V proj
    _Float16* xh  = (_Float16*)(vws + (size_t)BATCH * SEQS * EMBED);  // f16 x
    _Float16* aws = xh + ME;                            // f16 attn out
    _Float16* wqt = aws + ME;                           // f16 Wq^T
    _Float16* wot = wqt + (size_t)EMBED * EMBED;        // f16 Wo^T

    // prep: x -> f16; Wq,Wo -> transposed f16
    cvt_f32_f16<<<dim3(ME / (256 * 8)), 256, 0, stream>>>(x, xh);
    transpose_cvt<<<dim3(EMBED / 32, EMBED / 32), dim3(32, 8), 0, stream>>>(Wq, wqt, EMBED, EMBED);
    transpose_cvt<<<dim3(EMBED / 32, EMBED / 32), dim3(32, 8), 0, stream>>>(Wo, wot, EMBED, EMBED);

    // 1) Q = x @ Wq + bq  (f16 MFMA, fp32 out)
    gemm_f16<<<dim3(EMBED / 128, MROWS / 128), 256, 0, stream>>>(
        xh, wqt, bq, qws, MROWS, EMBED, EMBED);
    // 2) K,V projections (fp32)
    kv_proj<<<dim3(EMBED / 128, (BATCH * SEQS) / 8, 2), 128, 0, stream>>>(
        y, Wk, bk, Wv, bv, kws, vws);
    // 3) fused attention -> f16
    attn<<<dim3(SEQT / 64, BATCH * NH), 256, 0, stream>>>(qws, kws, vws, aws);
    // 4) out = attn_out @ Wo + bo
    gemm_f16<<<dim3(EMBED / 128, MROWS / 128), 256, 0, stream>>>(
        aws, wot, bo, out, MROWS, EMBED, EMBED);
}

// Round 3
// 429.639 us; speedup vs baseline: 2.4307x; 1.3013x over previous
//
#include <hip/hip_runtime.h>
#include <hip/hip_bf16.h>
#include <hip/hip_fp16.h>

#define EMBED 640
#define CROSS 768
#define NH 8
#define HEAD 80
#define BATCH 8
#define SEQT 4096
#define SEQS 77
#define MROWS (BATCH * SEQT)
#define LSTR 104   // LDS row stride (f16) for attn tiles: 96 data + 8 pad

typedef _Float16 half8 __attribute__((ext_vector_type(8)));
typedef float floatx4 __attribute__((ext_vector_type(4)));

__device__ __forceinline__ void lds_load16(const void* g, void* l) {
    __builtin_amdgcn_global_load_lds(
        (const __attribute__((address_space(1))) void*)g,
        (__attribute__((address_space(3))) void*)l, 16, 0, 0);
}

// ---------------------------------------------------------------------------
// fp32 -> f16 cast, 8 elems/thread.
// ---------------------------------------------------------------------------
__global__ __launch_bounds__(256) void cvt_f32_f16(
    const float* __restrict__ in, _Float16* __restrict__ out)
{
    size_t i = ((size_t)blockIdx.x * 256 + threadIdx.x) * 8;
    float4 a = *(const float4*)&in[i];
    float4 b = *(const float4*)&in[i + 4];
    half8 h;
    h[0] = (_Float16)a.x; h[1] = (_Float16)a.y;
    h[2] = (_Float16)a.z; h[3] = (_Float16)a.w;
    h[4] = (_Float16)b.x; h[5] = (_Float16)b.y;
    h[6] = (_Float16)b.z; h[7] = (_Float16)b.w;
    *(half8*)&out[i] = h;
}

__global__ __launch_bounds__(256) void zero_f16(_Float16* __restrict__ p, size_t n8)
{
    size_t i = (size_t)blockIdx.x * 256 + threadIdx.x;
    if (i < n8) *(half8*)&p[i * 8] = (half8){};
}

// ---------------------------------------------------------------------------
// W [K,N] fp32  ->  Wt [N,K] f16   (tiled transpose, 32x32)
// ---------------------------------------------------------------------------
__global__ __launch_bounds__(256) void transpose_cvt(
    const float* __restrict__ W, _Float16* __restrict__ Wt, int K, int N)
{
    __shared__ float t[32][33];
    const int k0 = blockIdx.y * 32, n0 = blockIdx.x * 32;
    for (int r = threadIdx.y; r < 32; r += 8)
        t[r][threadIdx.x] = W[(size_t)(k0 + r) * N + n0 + threadIdx.x];
    __syncthreads();
    for (int r = threadIdx.y; r < 32; r += 8)
        Wt[(size_t)(n0 + r) * K + k0 + threadIdx.x] = (_Float16)t[threadIdx.x][r];
}

// ---------------------------------------------------------------------------
// f16 MFMA GEMM (m97 structure): C = A[M,K] @ Bt[N,K]^T + bias, then *scale.
// HALF_OUT: write f16 (for Q, scale=1/sqrt(80) folded) else fp32.
// ---------------------------------------------------------------------------
template <bool HALF_OUT>
__global__ __launch_bounds__(256) void gemm_f16(
    const _Float16* __restrict__ A,   // [M,K] f16
    const _Float16* __restrict__ Bt,  // [N,K] f16
    const float* __restrict__ bias,
    void* __restrict__ Cout, int M, int N, int K, float scale)
{
    __shared__ _Float16 As[128 * 32];
    __shared__ _Float16 Bs[128 * 32];

    const int tid  = threadIdx.x;
    const int wave = tid >> 6;
    const int lane = tid & 63;
    const int quad = lane >> 4;
    const int l16  = lane & 15;
    const int m0 = blockIdx.y * 128, n0 = blockIdx.x * 128;
    const int wm = (wave >> 1) * 64, wn = (wave & 1) * 64;

    const int row = tid >> 2;
    const int kch = (tid & 3) * 8;

    floatx4 acc[4][4] = {};

    for (int k0 = 0; k0 < K; k0 += 32) {
        const _Float16* ga0 = &A [(size_t)(m0 + row)      * K + k0 + kch];
        const _Float16* ga1 = &A [(size_t)(m0 + 64 + row) * K + k0 + kch];
        const _Float16* gb0 = &Bt[(size_t)(n0 + row)      * K + k0 + kch];
        const _Float16* gb1 = &Bt[(size_t)(n0 + 64 + row) * K + k0 + kch];
        lds_load16(ga0, &As[wave * 512]);
        lds_load16(ga1, &As[2048 + wave * 512]);
        lds_load16(gb0, &Bs[wave * 512]);
        lds_load16(gb1, &Bs[2048 + wave * 512]);
        __syncthreads();

        half8 a[4], b[4];
        #pragma unroll
        for (int i = 0; i < 4; ++i)
            a[i] = *(const half8*)&As[(wm + i * 16 + l16) * 32 + quad * 8];
        #pragma unroll
        for (int j = 0; j < 4; ++j)
            b[j] = *(const half8*)&Bs[(wn + j * 16 + l16) * 32 + quad * 8];
        #pragma unroll
        for (int i = 0; i < 4; ++i)
            #pragma unroll
            for (int j = 0; j < 4; ++j)
                acc[i][j] = __builtin_amdgcn_mfma_f32_16x16x32_f16(
                    a[i], b[j], acc[i][j], 0, 0, 0);
        __syncthreads();
    }

    float bcol[4];
    #pragma unroll
    for (int j = 0; j < 4; ++j) bcol[j] = bias[n0 + wn + j * 16 + l16];
    #pragma unroll
    for (int i = 0; i < 4; ++i)
        #pragma unroll
        for (int r = 0; r < 4; ++r) {
            const int m = m0 + wm + i * 16 + quad * 4 + r;
            #pragma unroll
            for (int j = 0; j < 4; ++j) {
                float v = (acc[i][j][r] + bcol[j]) * scale;
                const size_t off = (size_t)m * N + n0 + wn + j * 16 + l16;
                if (HALF_OUT) ((_Float16*)Cout)[off] = (_Float16)v;
                else          ((float*)Cout)[off] = v;
            }
        }
}

// ---------------------------------------------------------------------------
// K/V projection -> f16, attention-friendly layouts:
//   kh [b*8+h][s(77)][d(80)]          (QK^T B-operand)
//   vth[b*8+h][d(80)][s(80, pad 0)]   (PV   B-operand, transposed)
// ---------------------------------------------------------------------------
__global__ __launch_bounds__(128) void kv_proj(
    const float* __restrict__ y,
    const float* __restrict__ Wk, const float* __restrict__ bk,
    const float* __restrict__ Wv, const float* __restrict__ bv,
    _Float16* __restrict__ kh, _Float16* __restrict__ vth)
{
    __shared__ __align__(16) float yl[8 * CROSS];
    const int tid = threadIdx.x;
    const int n  = blockIdx.x * 128 + tid;
    const int r0 = blockIdx.y * 8;
    const bool isV = blockIdx.z != 0;
    const float* W    = isV ? Wv : Wk;
    const float* bias = isV ? bv : bk;

    for (int i = tid * 4; i < 8 * CROSS; i += 128 * 4)
        *(float4*)&yl[i] = *(const float4*)&y[(size_t)r0 * CROSS + i];
    __syncthreads();

    float acc[8];
    #pragma unroll
    for (int r = 0; r < 8; ++r) acc[r] = bias[n];

    #pragma unroll 4
    for (int kk = 0; kk < CROSS; ++kk) {
        float w = W[(size_t)kk * EMBED + n];
        #pragma unroll
        for (int r = 0; r < 8; ++r) acc[r] += yl[r * CROSS + kk] * w;
    }

    const int h = n / HEAD, d = n % HEAD;
    #pragma unroll
    for (int r = 0; r < 8; ++r) {
        const int rr = r0 + r;
        const int b = rr / SEQS, s = rr % SEQS;
        const int bh = b * NH + h;
        if (isV) vth[(size_t)bh * (HEAD * 80) + d * 80 + s] = (_Float16)acc[r];
        else     kh [(size_t)bh * (SEQS * HEAD) + s * HEAD + d] = (_Float16)acc[r];
    }
}

// ---------------------------------------------------------------------------
// MFMA attention: per block = 64 q-rows x one (b,h).
// QK^T (D padded 80->96) -> softmax in C-layout regs (16-lane shuffle) ->
// P via LDS to A-layout -> PV (S padded 80->96, pads zero).
// q has 1/sqrt(80) pre-folded (gemm scale).
// ---------------------------------------------------------------------------
__global__ __launch_bounds__(256) void attn_mfma(
    const _Float16* __restrict__ qh,   // [M][EMBED], scaled
    const _Float16* __restrict__ kh,   // [64][77][80]
    const _Float16* __restrict__ vth,  // [64][80][80]
    _Float16* __restrict__ oh)         // [M][EMBED]
{
    __shared__ _Float16 Qs[64 * LSTR];
    __shared__ _Float16 Ks[80 * LSTR];
    __shared__ _Float16 Vt[80 * LSTR];
    __shared__ _Float16 Ps[64 * LSTR];

    const int tid = threadIdx.x;
    const int wave = tid >> 6, lane = tid & 63;
    const int quad = lane >> 4, l16 = lane & 15;
    const int bh = blockIdx.y;
    const int b = bh >> 3, h = bh & 7;
    const size_t grow0 = (size_t)b * SEQT + blockIdx.x * 64;  // first q row
    const half8 hz = {};

    // ---- stage Q, K, Vt (zero-padded to 96 cols), zero Ps pad cols ----
    for (int idx = tid; idx < 64 * 13; idx += 256) {
        int r = idx / 13, c = idx % 13;
        half8 v = hz;
        if (c < 10) v = *(const half8*)&qh[(grow0 + r) * EMBED + h * HEAD + c * 8];
        *(half8*)&Qs[r * LSTR + c * 8] = v;
    }
    for (int idx = tid; idx < 80 * 13; idx += 256) {
        int s = idx / 13, c = idx % 13;
        half8 v = hz;
        if (s < SEQS && c < 10)
            v = *(const half8*)&kh[(size_t)bh * (SEQS * HEAD) + s * HEAD + c * 8];
        *(half8*)&Ks[s * LSTR + c * 8] = v;
    }
    for (int idx = tid; idx < 80 * 13; idx += 256) {
        int d = idx / 13, c = idx % 13;
        half8 v = hz;
        if (c < 10) v = *(const half8*)&vth[(size_t)bh * (HEAD * 80) + d * 80 + c * 8];
        *(half8*)&Vt[d * LSTR + c * 8] = v;
    }
    for (int idx = tid; idx < 64 * 3; idx += 256) {
        int r = idx / 3, c = 10 + idx % 3;
        *(half8*)&Ps[r * LSTR + c * 8] = hz;
    }
    __syncthreads();

    // ---- QK^T: wave handles 16 rows; scores C-layout [row=quad*4+r][s=st*16+l16]
    floatx4 accs[5] = {};
    {
        half8 a[3];
        #pragma unroll
        for (int kk = 0; kk < 3; ++kk)
            a[kk] = *(const half8*)&Qs[(wave * 16 + l16) * LSTR + kk * 32 + quad * 8];
        #pragma unroll
        for (int st = 0; st < 5; ++st)
            #pragma unroll
            for (int kk = 0; kk < 3; ++kk) {
                half8 bb = *(const half8*)&Ks[(st * 16 + l16) * LSTR + kk * 32 + quad * 8];
                accs[st] = __builtin_amdgcn_mfma_f32_16x16x32_f16(a[kk], bb, accs[st], 0, 0, 0);
            }
    }
    // mask padded s (tile 4: s = 64 + l16 >= 77)
    if (l16 >= 13) {
        accs[4][0] = -1e30f; accs[4][1] = -1e30f;
        accs[4][2] = -1e30f; accs[4][3] = -1e30f;
    }

    // ---- softmax over s per row (16-lane shuffle reduce), write P (unnormalized)
    float recip[4];
    #pragma unroll
    for (int r = 0; r < 4; ++r) {
        float m = accs[0][r];
        #pragma unroll
        for (int st = 1; st < 5; ++st) m = fmaxf(m, accs[st][r]);
        m = fmaxf(m, __shfl_xor(m, 1));
        m = fmaxf(m, __shfl_xor(m, 2));
        m = fmaxf(m, __shfl_xor(m, 4));
        m = fmaxf(m, __shfl_xor(m, 8));
        float l = 0.f;
        const int row = wave * 16 + quad * 4 + r;
        #pragma unroll
        for (int st = 0; st < 5; ++st) {
            float e = __expf(accs[st][r] - m);   // pad lanes: exp(-1e30-m)=0
            l += e;
            Ps[row * LSTR + st * 16 + l16] = (_Float16)e;
        }
        l += __shfl_xor(l, 1);
        l += __shfl_xor(l, 2);
        l += __shfl_xor(l, 4);
        l += __shfl_xor(l, 8);
        recip[r] = 1.0f / l;
    }
    __syncthreads();

    // ---- PV: O[row][d] = sum_s P[row][s] * Vt[d][s]
    floatx4 acco[5] = {};
    {
        half8 a[3];
        #pragma unroll
        for (int kk = 0; kk < 3; ++kk)
            a[kk] = *(const half8*)&Ps[(wave * 16 + l16) * LSTR + kk * 32 + quad * 8];
        #pragma unroll
        for (int dt = 0; dt < 5; ++dt)
            #pragma unroll
            for (int kk = 0; kk < 3; ++kk) {
                half8 bb = *(const half8*)&Vt[(dt * 16 + l16) * LSTR + kk * 32 + quad * 8];
                acco[dt] = __builtin_amdgcn_mfma_f32_16x16x32_f16(a[kk], bb, acco[dt], 0, 0, 0);
            }
    }

    // ---- epilogue: normalize, store f16
    #pragma unroll
    for (int r = 0; r < 4; ++r) {
        const size_t grow = grow0 + wave * 16 + quad * 4 + r;
        #pragma unroll
        for (int dt = 0; dt < 5; ++dt)
            oh[grow * EMBED + h * HEAD + dt * 16 + l16] =
                (_Float16)(acco[dt][r] * recip[r]);
    }
}

// ---------------------------------------------------------------------------
extern "C" void kernel_launch(void* const* d_in, const int* in_sizes, int n_in,
                              void* d_out, int out_size, void* d_ws, size_t ws_size,
                              hipStream_t stream)
{
    const float* x  = (const float*)d_in[0];
    const float* y  = (const float*)d_in[1];
    const float* Wq = (const float*)d_in[2];
    const float* bq = (const float*)d_in[3];
    const float* Wk = (const float*)d_in[4];
    const float* bk = (const float*)d_in[5];
    const float* Wv = (const float*)d_in[6];
    const float* bv = (const float*)d_in[7];
    const float* Wo = (const float*)d_in[8];
    const float* bo = (const float*)d_in[9];
    float* out = (float*)d_out;

    const size_t ME = (size_t)MROWS * EMBED;
    _Float16* xh  = (_Float16*)d_ws;                 // [M][640] f16 x
    _Float16* qh  = xh + ME;                         // [M][640] f16 Q (scaled)
    _Float16* ah  = qh + ME;                         // [M][640] f16 attn out
    _Float16* kh  = ah + ME;                         // [64][77][80]
    _Float16* vth = kh + (size_t)BATCH * NH * SEQS * HEAD;   // [64][80][80]
    _Float16* wqt = vth + (size_t)BATCH * NH * HEAD * 80;    // [640][640]
    _Float16* wot = wqt + (size_t)EMBED * EMBED;

    // prep
    cvt_f32_f16<<<dim3(ME / (256 * 8)), 256, 0, stream>>>(x, xh);
    transpose_cvt<<<dim3(EMBED / 32, EMBED / 32), dim3(32, 8), 0, stream>>>(Wq, wqt, EMBED, EMBED);
    transpose_cvt<<<dim3(EMBED / 32, EMBED / 32), dim3(32, 8), 0, stream>>>(Wo, wot, EMBED, EMBED);
    zero_f16<<<dim3(((size_t)BATCH * NH * HEAD * 80 / 8 + 255) / 256), 256, 0, stream>>>(
        vth, (size_t)BATCH * NH * HEAD * 80 / 8);

    // 1) Q = (x @ Wq + bq) * 1/sqrt(80), f16 out
    gemm_f16<true><<<dim3(EMBED / 128, MROWS / 128), 256, 0, stream>>>(
        xh, wqt, bq, qh, MROWS, EMBED, EMBED, 0.11180339887498949f);
    // 2) K,V projections -> f16 attention layouts
    kv_proj<<<dim3(EMBED / 128, (BATCH * SEQS) / 8, 2), 128, 0, stream>>>(
        y, Wk, bk, Wv, bv, kh, vth);
    // 3) MFMA attention -> f16
    attn_mfma<<<dim3(SEQT / 64, BATCH * NH), 256, 0, stream>>>(qh, kh, vth, ah);
    // 4) out = attn_out @ Wo + bo (fp32 out)
    gemm_f16<false><<<dim3(EMBED / 128, MROWS / 128), 256, 0, stream>>>(
        ah, wot, bo, out, MROWS, EMBED, EMBED, 1.0f);
}

// Round 4
// 355.365 us; speedup vs baseline: 2.9388x; 1.2090x over previous
//
#include <hip/hip_runtime.h>
#include <hip/hip_bf16.h>
#include <hip/hip_fp16.h>

#define EMBED 640
#define CROSS 768
#define NH 8
#define HEAD 80
#define BATCH 8
#define SEQT 4096
#define SEQS 77
#define MROWS (BATCH * SEQT)
#define LSTR 104   // LDS row stride (f16) for attn tiles: 96 data + 8 pad

typedef _Float16 half8 __attribute__((ext_vector_type(8)));
typedef float floatx4 __attribute__((ext_vector_type(4)));

__device__ __forceinline__ void lds_load16(const void* g, void* l) {
    __builtin_amdgcn_global_load_lds(
        (const __attribute__((address_space(1))) void*)g,
        (__attribute__((address_space(3))) void*)l, 16, 0, 0);
}

// ---------------------------------------------------------------------------
// fp32 -> f16 cast, 8 elems/thread (n divisible by 2048*... exact grids used).
// ---------------------------------------------------------------------------
__global__ __launch_bounds__(256) void cvt_f32_f16(
    const float* __restrict__ in, _Float16* __restrict__ out)
{
    size_t i = ((size_t)blockIdx.x * 256 + threadIdx.x) * 8;
    float4 a = *(const float4*)&in[i];
    float4 b = *(const float4*)&in[i + 4];
    half8 h;
    h[0] = (_Float16)a.x; h[1] = (_Float16)a.y;
    h[2] = (_Float16)a.z; h[3] = (_Float16)a.w;
    h[4] = (_Float16)b.x; h[5] = (_Float16)b.y;
    h[6] = (_Float16)b.z; h[7] = (_Float16)b.w;
    *(half8*)&out[i] = h;
}

// y [616*768] fp32 -> yh [640][768] f16, rows 616..639 zeroed.
__global__ __launch_bounds__(256) void cvt_y_f16(
    const float* __restrict__ y, _Float16* __restrict__ yh)
{
    size_t i = ((size_t)blockIdx.x * 256 + threadIdx.x) * 8;  // < 640*768
    half8 h = {};
    if (i < (size_t)BATCH * SEQS * CROSS) {
        float4 a = *(const float4*)&y[i];
        float4 b = *(const float4*)&y[i + 4];
        h[0] = (_Float16)a.x; h[1] = (_Float16)a.y;
        h[2] = (_Float16)a.z; h[3] = (_Float16)a.w;
        h[4] = (_Float16)b.x; h[5] = (_Float16)b.y;
        h[6] = (_Float16)b.z; h[7] = (_Float16)b.w;
    }
    *(half8*)&yh[i] = h;
}

__global__ __launch_bounds__(256) void zero_f16(_Float16* __restrict__ p, size_t n8)
{
    size_t i = (size_t)blockIdx.x * 256 + threadIdx.x;
    if (i < n8) *(half8*)&p[i * 8] = (half8){};
}

// ---------------------------------------------------------------------------
// W [K,N] fp32  ->  Wt [N,K] f16   (tiled transpose, 32x32)
// ---------------------------------------------------------------------------
__global__ __launch_bounds__(256) void transpose_cvt(
    const float* __restrict__ W, _Float16* __restrict__ Wt, int K, int N)
{
    __shared__ float t[32][33];
    const int k0 = blockIdx.y * 32, n0 = blockIdx.x * 32;
    for (int r = threadIdx.y; r < 32; r += 8)
        t[r][threadIdx.x] = W[(size_t)(k0 + r) * N + n0 + threadIdx.x];
    __syncthreads();
    for (int r = threadIdx.y; r < 32; r += 8)
        Wt[(size_t)(n0 + r) * K + k0 + threadIdx.x] = (_Float16)t[threadIdx.x][r];
}

// ---------------------------------------------------------------------------
// f16 MFMA GEMM (m97 structure): C = A[M,K] @ Bt[N,K]^T + bias, then *scale.
// HALF_OUT: write f16 (for Q, scale=1/sqrt(80) folded) else fp32.
// ---------------------------------------------------------------------------
template <bool HALF_OUT>
__global__ __launch_bounds__(256) void gemm_f16(
    const _Float16* __restrict__ A,   // [M,K] f16
    const _Float16* __restrict__ Bt,  // [N,K] f16
    const float* __restrict__ bias,
    void* __restrict__ Cout, int M, int N, int K, float scale)
{
    __shared__ _Float16 As[128 * 32];
    __shared__ _Float16 Bs[128 * 32];

    const int tid  = threadIdx.x;
    const int wave = tid >> 6;
    const int lane = tid & 63;
    const int quad = lane >> 4;
    const int l16  = lane & 15;
    const int m0 = blockIdx.y * 128, n0 = blockIdx.x * 128;
    const int wm = (wave >> 1) * 64, wn = (wave & 1) * 64;

    const int row = tid >> 2;
    const int kch = (tid & 3) * 8;

    floatx4 acc[4][4] = {};

    for (int k0 = 0; k0 < K; k0 += 32) {
        const _Float16* ga0 = &A [(size_t)(m0 + row)      * K + k0 + kch];
        const _Float16* ga1 = &A [(size_t)(m0 + 64 + row) * K + k0 + kch];
        const _Float16* gb0 = &Bt[(size_t)(n0 + row)      * K + k0 + kch];
        const _Float16* gb1 = &Bt[(size_t)(n0 + 64 + row) * K + k0 + kch];
        lds_load16(ga0, &As[wave * 512]);
        lds_load16(ga1, &As[2048 + wave * 512]);
        lds_load16(gb0, &Bs[wave * 512]);
        lds_load16(gb1, &Bs[2048 + wave * 512]);
        __syncthreads();

        half8 a[4], b[4];
        #pragma unroll
        for (int i = 0; i < 4; ++i)
            a[i] = *(const half8*)&As[(wm + i * 16 + l16) * 32 + quad * 8];
        #pragma unroll
        for (int j = 0; j < 4; ++j)
            b[j] = *(const half8*)&Bs[(wn + j * 16 + l16) * 32 + quad * 8];
        #pragma unroll
        for (int i = 0; i < 4; ++i)
            #pragma unroll
            for (int j = 0; j < 4; ++j)
                acc[i][j] = __builtin_amdgcn_mfma_f32_16x16x32_f16(
                    a[i], b[j], acc[i][j], 0, 0, 0);
        __syncthreads();
    }

    float bcol[4];
    #pragma unroll
    for (int j = 0; j < 4; ++j) bcol[j] = bias[n0 + wn + j * 16 + l16];
    #pragma unroll
    for (int i = 0; i < 4; ++i)
        #pragma unroll
        for (int r = 0; r < 4; ++r) {
            const int m = m0 + wm + i * 16 + quad * 4 + r;
            #pragma unroll
            for (int j = 0; j < 4; ++j) {
                float v = (acc[i][j][r] + bcol[j]) * scale;
                const size_t off = (size_t)m * N + n0 + wn + j * 16 + l16;
                if (HALF_OUT) ((_Float16*)Cout)[off] = (_Float16)v;
                else          ((float*)Cout)[off] = v;
            }
        }
}

// ---------------------------------------------------------------------------
// K/V projection via MFMA. 64x64 tiles, 4 waves (wave w = cols w*16..w*16+15).
// A = yh [640][768] f16 (rows 616+ zero), B = Wkt/Wvt [640][768] f16.
// Epilogue scatters f16 into attention layouts:
//   kh [bh][s(77)][d(80)], vth[bh][d(80)][s(80, pads pre-zeroed)]
// ---------------------------------------------------------------------------
__global__ __launch_bounds__(256) void kv_gemm(
    const _Float16* __restrict__ yh,
    const _Float16* __restrict__ Wkt, const _Float16* __restrict__ Wvt,
    const float* __restrict__ bk, const float* __restrict__ bv,
    _Float16* __restrict__ kh, _Float16* __restrict__ vth)
{
    __shared__ _Float16 As[64 * 32];
    __shared__ _Float16 Bs[64 * 32];

    const int tid = threadIdx.x;
    const int wave = tid >> 6, lane = tid & 63;
    const int quad = lane >> 4, l16 = lane & 15;
    const int m0 = blockIdx.y * 64, n0 = blockIdx.x * 64;
    const bool isV = blockIdx.z != 0;
    const _Float16* Bt = isV ? Wvt : Wkt;
    const float* bias  = isV ? bv : bk;

    const int row = tid >> 2;        // 0..63
    const int kch = (tid & 3) * 8;   // k chunk (8 f16 = 16 B)

    floatx4 acc[4] = {};

    for (int k0 = 0; k0 < CROSS; k0 += 32) {
        lds_load16(&yh[(size_t)(m0 + row) * CROSS + k0 + kch], &As[wave * 512]);
        lds_load16(&Bt[(size_t)(n0 + row) * CROSS + k0 + kch], &Bs[wave * 512]);
        __syncthreads();
        half8 b = *(const half8*)&Bs[(wave * 16 + l16) * 32 + quad * 8];
        #pragma unroll
        for (int i = 0; i < 4; ++i) {
            half8 a = *(const half8*)&As[(i * 16 + l16) * 32 + quad * 8];
            acc[i] = __builtin_amdgcn_mfma_f32_16x16x32_f16(a, b, acc[i], 0, 0, 0);
        }
        __syncthreads();
    }

    const int n = n0 + wave * 16 + l16;     // 0..639
    const int h = n / HEAD, d = n % HEAD;
    const float bb = bias[n];
    #pragma unroll
    for (int i = 0; i < 4; ++i)
        #pragma unroll
        for (int r = 0; r < 4; ++r) {
            const int m = m0 + i * 16 + quad * 4 + r;
            if (m >= BATCH * SEQS) continue;
            const int b_ = m / SEQS, s = m % SEQS;
            const int bh = b_ * NH + h;
            const float v = acc[i][r] + bb;
            if (isV) vth[(size_t)bh * (HEAD * 80) + d * 80 + s] = (_Float16)v;
            else     kh [(size_t)bh * (SEQS * HEAD) + s * HEAD + d] = (_Float16)v;
        }
}

// ---------------------------------------------------------------------------
// MFMA attention: per block = 64 q-rows x one (b,h).
// ---------------------------------------------------------------------------
__global__ __launch_bounds__(256) void attn_mfma(
    const _Float16* __restrict__ qh,   // [M][EMBED], 1/sqrt(80) pre-folded
    const _Float16* __restrict__ kh,   // [64][77][80]
    const _Float16* __restrict__ vth,  // [64][80][80]
    _Float16* __restrict__ oh)         // [M][EMBED]
{
    __shared__ _Float16 Qs[64 * LSTR];
    __shared__ _Float16 Ks[80 * LSTR];
    __shared__ _Float16 Vt[80 * LSTR];
    __shared__ _Float16 Ps[64 * LSTR];

    const int tid = threadIdx.x;
    const int wave = tid >> 6, lane = tid & 63;
    const int quad = lane >> 4, l16 = lane & 15;
    const int bh = blockIdx.y;
    const int b = bh >> 3, h = bh & 7;
    const size_t grow0 = (size_t)b * SEQT + blockIdx.x * 64;
    const half8 hz = {};

    for (int idx = tid; idx < 64 * 13; idx += 256) {
        int r = idx / 13, c = idx % 13;
        half8 v = hz;
        if (c < 10) v = *(const half8*)&qh[(grow0 + r) * EMBED + h * HEAD + c * 8];
        *(half8*)&Qs[r * LSTR + c * 8] = v;
    }
    for (int idx = tid; idx < 80 * 13; idx += 256) {
        int s = idx / 13, c = idx % 13;
        half8 v = hz;
        if (s < SEQS && c < 10)
            v = *(const half8*)&kh[(size_t)bh * (SEQS * HEAD) + s * HEAD + c * 8];
        *(half8*)&Ks[s * LSTR + c * 8] = v;
    }
    for (int idx = tid; idx < 80 * 13; idx += 256) {
        int d = idx / 13, c = idx % 13;
        half8 v = hz;
        if (c < 10) v = *(const half8*)&vth[(size_t)bh * (HEAD * 80) + d * 80 + c * 8];
        *(half8*)&Vt[d * LSTR + c * 8] = v;
    }
    for (int idx = tid; idx < 64 * 3; idx += 256) {
        int r = idx / 3, c = 10 + idx % 3;
        *(half8*)&Ps[r * LSTR + c * 8] = hz;
    }
    __syncthreads();

    floatx4 accs[5] = {};
    {
        half8 a[3];
        #pragma unroll
        for (int kk = 0; kk < 3; ++kk)
            a[kk] = *(const half8*)&Qs[(wave * 16 + l16) * LSTR + kk * 32 + quad * 8];
        #pragma unroll
        for (int st = 0; st < 5; ++st)
            #pragma unroll
            for (int kk = 0; kk < 3; ++kk) {
                half8 bb = *(const half8*)&Ks[(st * 16 + l16) * LSTR + kk * 32 + quad * 8];
                accs[st] = __builtin_amdgcn_mfma_f32_16x16x32_f16(a[kk], bb, accs[st], 0, 0, 0);
            }
    }
    if (l16 >= 13) {
        accs[4][0] = -1e30f; accs[4][1] = -1e30f;
        accs[4][2] = -1e30f; accs[4][3] = -1e30f;
    }

    float recip[4];
    #pragma unroll
    for (int r = 0; r < 4; ++r) {
        float m = accs[0][r];
        #pragma unroll
        for (int st = 1; st < 5; ++st) m = fmaxf(m, accs[st][r]);
        m = fmaxf(m, __shfl_xor(m, 1));
        m = fmaxf(m, __shfl_xor(m, 2));
        m = fmaxf(m, __shfl_xor(m, 4));
        m = fmaxf(m, __shfl_xor(m, 8));
        float l = 0.f;
        const int row = wave * 16 + quad * 4 + r;
        #pragma unroll
        for (int st = 0; st < 5; ++st) {
            float e = __expf(accs[st][r] - m);
            l += e;
            Ps[row * LSTR + st * 16 + l16] = (_Float16)e;
        }
        l += __shfl_xor(l, 1);
        l += __shfl_xor(l, 2);
        l += __shfl_xor(l, 4);
        l += __shfl_xor(l, 8);
        recip[r] = 1.0f / l;
    }
    __syncthreads();

    floatx4 acco[5] = {};
    {
        half8 a[3];
        #pragma unroll
        for (int kk = 0; kk < 3; ++kk)
            a[kk] = *(const half8*)&Ps[(wave * 16 + l16) * LSTR + kk * 32 + quad * 8];
        #pragma unroll
        for (int dt = 0; dt < 5; ++dt)
            #pragma unroll
            for (int kk = 0; kk < 3; ++kk) {
                half8 bb = *(const half8*)&Vt[(dt * 16 + l16) * LSTR + kk * 32 + quad * 8];
                acco[dt] = __builtin_amdgcn_mfma_f32_16x16x32_f16(a[kk], bb, acco[dt], 0, 0, 0);
            }
    }

    #pragma unroll
    for (int r = 0; r < 4; ++r) {
        const size_t grow = grow0 + wave * 16 + quad * 4 + r;
        #pragma unroll
        for (int dt = 0; dt < 5; ++dt)
            oh[grow * EMBED + h * HEAD + dt * 16 + l16] =
                (_Float16)(acco[dt][r] * recip[r]);
    }
}

// ---------------------------------------------------------------------------
extern "C" void kernel_launch(void* const* d_in, const int* in_sizes, int n_in,
                              void* d_out, int out_size, void* d_ws, size_t ws_size,
                              hipStream_t stream)
{
    const float* x  = (const float*)d_in[0];
    const float* y  = (const float*)d_in[1];
    const float* Wq = (const float*)d_in[2];
    const float* bq = (const float*)d_in[3];
    const float* Wk = (const float*)d_in[4];
    const float* bk = (const float*)d_in[5];
    const float* Wv = (const float*)d_in[6];
    const float* bv = (const float*)d_in[7];
    const float* Wo = (const float*)d_in[8];
    const float* bo = (const float*)d_in[9];
    float* out = (float*)d_out;

    const size_t ME = (size_t)MROWS * EMBED;
    _Float16* xh  = (_Float16*)d_ws;                          // [M][640]
    _Float16* qh  = xh + ME;                                  // [M][640]
    _Float16* ah  = qh + ME;                                  // [M][640]
    _Float16* kh  = ah + ME;                                  // [64][77][80]
    _Float16* vth = kh  + (size_t)BATCH * NH * SEQS * HEAD;   // [64][80][80]
    _Float16* wqt = vth + (size_t)BATCH * NH * HEAD * 80;     // [640][640]
    _Float16* wot = wqt + (size_t)EMBED * EMBED;              // [640][640]
    _Float16* yh  = wot + (size_t)EMBED * EMBED;              // [640][768]
    _Float16* wkt = yh  + (size_t)640 * CROSS;                // [640][768]
    _Float16* wvt = wkt + (size_t)EMBED * CROSS;              // [640][768]

    // prep
    cvt_f32_f16<<<dim3(ME / (256 * 8)), 256, 0, stream>>>(x, xh);
    transpose_cvt<<<dim3(EMBED / 32, EMBED / 32), dim3(32, 8), 0, stream>>>(Wq, wqt, EMBED, EMBED);
    transpose_cvt<<<dim3(EMBED / 32, EMBED / 32), dim3(32, 8), 0, stream>>>(Wo, wot, EMBED, EMBED);
    transpose_cvt<<<dim3(EMBED / 32, CROSS / 32), dim3(32, 8), 0, stream>>>(Wk, wkt, CROSS, EMBED);
    transpose_cvt<<<dim3(EMBED / 32, CROSS / 32), dim3(32, 8), 0, stream>>>(Wv, wvt, CROSS, EMBED);
    cvt_y_f16<<<dim3(640 * CROSS / (256 * 8)), 256, 0, stream>>>(y, yh);
    zero_f16<<<dim3(((size_t)BATCH * NH * HEAD * 80 / 8 + 255) / 256), 256, 0, stream>>>(
        vth, (size_t)BATCH * NH * HEAD * 80 / 8);

    // 1) Q = (x @ Wq + bq) * 1/sqrt(80), f16 out
    gemm_f16<true><<<dim3(EMBED / 128, MROWS / 128), 256, 0, stream>>>(
        xh, wqt, bq, qh, MROWS, EMBED, EMBED, 0.11180339887498949f);
    // 2) K,V projections via MFMA -> attention layouts
    kv_gemm<<<dim3(EMBED / 64, 640 / 64, 2), 256, 0, stream>>>(
        yh, wkt, wvt, bk, bv, kh, vth);
    // 3) MFMA attention -> f16
    attn_mfma<<<dim3(SEQT / 64, BATCH * NH), 256, 0, stream>>>(qh, kh, vth, ah);
    // 4) out = attn_out @ Wo + bo (fp32 out)
    gemm_f16<false><<<dim3(EMBED / 128, MROWS / 128), 256, 0, stream>>>(
        ah, wot, bo, out, MROWS, EMBED, EMBED, 1.0f);
}